// Round 4
// baseline (946.922 us; speedup 1.0000x reference)
//
#include <hip/hip_runtime.h>
#include <hip/hip_bf16.h>

typedef unsigned int u32;
typedef __attribute__((ext_vector_type(8))) short short8;
typedef __attribute__((ext_vector_type(4))) float f32x4;

#define NN 50000
#define NPAD 50048       // padded to 64-row multiple for MFMA blocks
#define EE 800000
#define GG 64
#define HH 3
#define CC 64
#define IN_DIM 75
#define KP1 96           // padded K for layer-1 GEMM
#define HC 192           // H*C
#define TOTAL (EE + NN)  // edge entries incl self loops

// ---------------- helpers ----------------
__device__ __forceinline__ u32 fmap(float f) {
    u32 u = __float_as_uint(f);
    return (u & 0x80000000u) ? ~u : (u | 0x80000000u);
}
__device__ __forceinline__ float funmap(u32 m) {
    u32 u = (m & 0x80000000u) ? (m ^ 0x80000000u) : ~m;
    return __uint_as_float(u);
}

// ---------------- degree + edge-attr sum ----------------
__global__ void k_deg(const int* __restrict__ ei, const float* __restrict__ eattr,
                      int* __restrict__ deg, float* __restrict__ attrsum) {
    int e = blockIdx.x * 256 + threadIdx.x;
    if (e >= EE) return;
    int d = ei[EE + e];
    atomicAdd(&deg[d], 1);
    atomicAdd(&attrsum[d], eattr[e]);
}

// ---------------- prefix scan (deg+1) : 2-level ----------------
__global__ void k_scan1(const int* __restrict__ deg, u32* __restrict__ startv,
                        u32* __restrict__ blocksum) {
    __shared__ u32 sh[1024];
    int t = threadIdx.x;
    int n = blockIdx.x * 1024 + t;
    u32 v = (n < NN) ? (u32)(deg[n] + 1) : 0u;
    u32 val = v;
    sh[t] = val;
    __syncthreads();
    for (int off = 1; off < 1024; off <<= 1) {
        u32 y = (t >= off) ? sh[t - off] : 0u;
        __syncthreads();
        val += y;
        sh[t] = val;
        __syncthreads();
    }
    if (n < NN) startv[n] = val - v;   // block-exclusive
    if (t == 0) blocksum[blockIdx.x] = sh[1023];
}

__global__ void k_scan2(u32* __restrict__ blocksum, int nb) {
    if (threadIdx.x == 0) {
        u32 acc = 0;
        for (int b = 0; b < nb; b++) { u32 t = blocksum[b]; blocksum[b] = acc; acc += t; }
    }
}

// also accumulates per-graph node counts (pcnt) for pooling mean
__global__ void k_scan3(u32* __restrict__ startv, const u32* __restrict__ blocksum,
                        u32* __restrict__ cursor, const int* __restrict__ batch,
                        int* __restrict__ pcnt) {
    int n = blockIdx.x * 256 + threadIdx.x;
    if (n >= NN) return;
    u32 s = startv[n] + blocksum[n >> 10];
    startv[n] = s;
    cursor[n] = s;
    atomicAdd(&pcnt[batch[n]], 1);
}

// fill CSR-ordered streams: srcP/eaP/dstP packed by destination segment; iOf maps pos->entry
__global__ void k_fill(const int* __restrict__ ei, const float* __restrict__ eattr,
                       const float* __restrict__ attrsum, const int* __restrict__ deg,
                       u32* __restrict__ cursor, int* __restrict__ srcP,
                       int* __restrict__ dstP, float* __restrict__ eaP,
                       u32* __restrict__ iOf) {
    int i = blockIdx.x * 256 + threadIdx.x;
    if (i >= TOTAL) return;
    int s, d;
    float ea;
    if (i < EE) {
        s = ei[i]; d = ei[EE + i]; ea = eattr[i];
    } else {
        s = d = i - EE;
        ea = attrsum[s] / fmaxf((float)deg[s], 1.f);
    }
    u32 pos = atomicAdd(&cursor[d], 1u);
    srcP[pos] = s;
    dstP[pos] = d;
    eaP[pos] = ea;
    iOf[pos] = (u32)i;
}

// ---------------- prep: Wt conversions + pmax init + wedot ----------------
__global__ void k_prep(const float* __restrict__ W1, const float* __restrict__ W2,
                       const float* __restrict__ We1, const float* __restrict__ ae1,
                       const float* __restrict__ We2, const float* __restrict__ ae2,
                       __hip_bfloat16* __restrict__ Wt1, __hip_bfloat16* __restrict__ Wt2,
                       u32* __restrict__ pmax, float* __restrict__ wedot) {
    int i = blockIdx.x * 256 + threadIdx.x;
    if (i < HC * KP1) {
        int j = i / KP1, k = i - j * KP1;
        Wt1[i] = __float2bfloat16(k < IN_DIM ? W1[k * HC + j] : 0.f);
    }
    if (i < HC * HC) {
        int j = i / HC, k = i - j * HC;
        Wt2[i] = __float2bfloat16(W2[k * HC + j]);
    }
    if (i < GG * HC) pmax[i] = 0x007FFFFFu;   // fmap(-inf)
    if (blockIdx.x == 0) {
        int w = threadIdx.x >> 6, c = threadIdx.x & 63;
        for (int dd = w; dd < 6; dd += 4) {
            int layer = dd / 3, h = dd - 3 * layer;
            const float* We = layer ? We2 : We1;
            const float* ae = layer ? ae2 : ae1;
            float v = We[h * 64 + c] * ae[h * 64 + c];
#pragma unroll
            for (int off = 32; off; off >>= 1) v += __shfl_xor(v, off, 64);
            if (c == 0) wedot[dd] = v;
        }
    }
}

// xb[NPAD][KP1] bf16, zero-padded rows and k>=IN_DIM
__global__ void k_xconv(const float* __restrict__ x, __hip_bfloat16* __restrict__ xb) {
    int i = blockIdx.x * 256 + threadIdx.x;
    if (i >= NPAD * KP1) return;
    int n = i / KP1, k = i - n * KP1;
    float v = (n < NN && k < IN_DIM) ? x[n * IN_DIM + k] : 0.f;
    xb[i] = __float2bfloat16(v);
}

// ---------------- MFMA GEMM + fused attdot epilogue ----------------
// out[NPAD,192] = A[NPAD,KPAD] @ Wt^T;  asrc/adst[n,h] = sum_c out[n,h*64+c]*a{s,d}w[h*64+c]
// A row-major bf16 [NPAD][KPAD]; Wt row-major bf16 [192][KPAD] (Wt[j][k]=W[k][j]).
// Block: 256 thr = 4 waves; 64 rows x 192 cols per block; 12 col-frags per wave.
template <int KPAD>
__global__ __launch_bounds__(256) void k_mfma_gemm(const __hip_bfloat16* __restrict__ A,
                                                   const __hip_bfloat16* __restrict__ Wt,
                                                   const float* __restrict__ asrcw,
                                                   const float* __restrict__ adstw,
                                                   float* __restrict__ out,
                                                   float* __restrict__ asrc,
                                                   float* __restrict__ adst) {
    int wid = threadIdx.x >> 6;
    int lane = threadIdx.x & 63;
    int r0 = blockIdx.x * 64 + wid * 16;
    int lr = lane & 15;     // A: row-in-16, B: col-in-16
    int g = lane >> 4;      // k-subgroup (8 elems each)
    const short* Ab = (const short*)A;
    const short* Wb = (const short*)Wt;
    f32x4 acc[12];
#pragma unroll
    for (int f = 0; f < 12; f++) acc[f] = (f32x4){0.f, 0.f, 0.f, 0.f};
#pragma unroll
    for (int k0 = 0; k0 < KPAD; k0 += 32) {
        short8 a = *(const short8*)(Ab + (size_t)(r0 + lr) * KPAD + k0 + 8 * g);
#pragma unroll
        for (int f = 0; f < 12; f++) {
            short8 b = *(const short8*)(Wb + (size_t)(f * 16 + lr) * KPAD + k0 + 8 * g);
            acc[f] = __builtin_amdgcn_mfma_f32_16x16x32_bf16(a, b, acc[f], 0, 0, 0);
        }
    }
    int rbase = r0 + 4 * g;   // D: col = lane&15, row = 4*(lane>>4)+reg
#pragma unroll
    for (int f = 0; f < 12; f++) {
        int col = f * 16 + lr;
#pragma unroll
        for (int r = 0; r < 4; r++) {
            int row = rbase + r;
            if (row < NN) out[(size_t)row * HC + col] = acc[f][r];
        }
    }
    // fused attdot: per row, per head, weighted col-sum reduced across 16-lane group
    float asw[12], adw[12];
#pragma unroll
    for (int f = 0; f < 12; f++) {
        asw[f] = asrcw[f * 16 + lr];
        adw[f] = adstw[f * 16 + lr];
    }
#pragma unroll
    for (int h = 0; h < 3; h++) {
#pragma unroll
        for (int r = 0; r < 4; r++) {
            float p = acc[4 * h][r] * asw[4 * h] + acc[4 * h + 1][r] * asw[4 * h + 1] +
                      acc[4 * h + 2][r] * asw[4 * h + 2] + acc[4 * h + 3][r] * asw[4 * h + 3];
            float q = acc[4 * h][r] * adw[4 * h] + acc[4 * h + 1][r] * adw[4 * h + 1] +
                      acc[4 * h + 2][r] * adw[4 * h + 2] + acc[4 * h + 3][r] * adw[4 * h + 3];
#pragma unroll
            for (int off = 1; off < 16; off <<= 1) {
                p += __shfl_xor(p, off, 64);
                q += __shfl_xor(q, off, 64);
            }
            int row = rbase + r;
            if (lr == 0 && row < NN) {
                asrc[row * 3 + h] = p;
                adst[row * 3 + h] = q;
            }
        }
    }
}

// ---------------- fused alpha + softmax(no-max) + aggregation (+pool on layer 2) -------
// Computes alpha inline, e=exp(lrelu(alpha)) (no max subtraction: alpha bounded ~15),
// writes unnormalized e to eP (packed), rdenom = 1/(sum+eps), and either h->bf16 (layer1)
// or pooled atomics (layer2).
template <int LAYER2>
__global__ void k_gatherSM(const u32* __restrict__ startv, const int* __restrict__ deg,
                           const int* __restrict__ srcP, const float* __restrict__ eaP,
                           const float* __restrict__ asrc, const float* __restrict__ adst,
                           const float* __restrict__ wedot, int woff,
                           float* __restrict__ eP, const float* __restrict__ xh,
                           const float* __restrict__ bias, float* __restrict__ rdenom,
                           __hip_bfloat16* __restrict__ hb, const int* __restrict__ batch,
                           float* __restrict__ psum, u32* __restrict__ pmax) {
    int n = blockIdx.x;
    int j = threadIdx.x;      // 0..191
    int h = j >> 6, c = j & 63;
    u32 st = startv[n];
    int L = deg[n] + 1;
    float wd = wedot[woff + h];
    float adx = adst[n * 3 + h];
    const int* sp = srcP + st;
    const float* ep = eaP + st;
    float* eo = eP + (size_t)st * 3 + h;

    float acc = 0.f, ssum = 0.f;
    int p = 0;
    for (; p + 4 <= L; p += 4) {
        int s0 = sp[p], s1 = sp[p + 1], s2 = sp[p + 2], s3 = sp[p + 3];
        float ea0 = ep[p], ea1 = ep[p + 1], ea2 = ep[p + 2], ea3 = ep[p + 3];
        float a0 = asrc[s0 * 3 + h] + adx + ea0 * wd;
        float a1 = asrc[s1 * 3 + h] + adx + ea1 * wd;
        float a2 = asrc[s2 * 3 + h] + adx + ea2 * wd;
        float a3 = asrc[s3 * 3 + h] + adx + ea3 * wd;
        a0 = (a0 > 0.f) ? a0 : 0.2f * a0;
        a1 = (a1 > 0.f) ? a1 : 0.2f * a1;
        a2 = (a2 > 0.f) ? a2 : 0.2f * a2;
        a3 = (a3 > 0.f) ? a3 : 0.2f * a3;
        float e0 = __expf(a0), e1 = __expf(a1), e2 = __expf(a2), e3 = __expf(a3);
        float x0 = xh[(size_t)s0 * HC + j];
        float x1 = xh[(size_t)s1 * HC + j];
        float x2 = xh[(size_t)s2 * HC + j];
        float x3 = xh[(size_t)s3 * HC + j];
        if (c == 0) {
            eo[3 * p] = e0;
            eo[3 * (p + 1)] = e1;
            eo[3 * (p + 2)] = e2;
            eo[3 * (p + 3)] = e3;
        }
        acc += e0 * x0;
        acc += e1 * x1;
        acc += e2 * x2;
        acc += e3 * x3;
        ssum += (e0 + e1) + (e2 + e3);
    }
    for (; p < L; p++) {
        int s0 = sp[p];
        float a0 = asrc[s0 * 3 + h] + adx + ep[p] * wd;
        a0 = (a0 > 0.f) ? a0 : 0.2f * a0;
        float e0 = __expf(a0);
        float x0 = xh[(size_t)s0 * HC + j];
        if (c == 0) eo[3 * p] = e0;
        acc += e0 * x0;
        ssum += e0;
    }
    float r = 1.f / (ssum + 1e-16f);
    if (c == 0) rdenom[n * 3 + h] = r;
    float o = acc * r + bias[j];
    o = (o > 0.f) ? o : expm1f(o);
    if (LAYER2) {
        int gi = batch[n];
        atomicAdd(&psum[gi * HC + j], o);
        atomicMax(&pmax[gi * HC + j], fmap(o));
    } else {
        hb[(size_t)n * HC + j] = __float2bfloat16(o);
    }
}

// ---------------- normalized attn, scatter-write in original entry order ----------------
__global__ void k_attnout(const u32* __restrict__ iOf, const int* __restrict__ dstP,
                          const float* __restrict__ eP, const float* __restrict__ rdenom,
                          float* __restrict__ attn) {
    int pos = blockIdx.x * 256 + threadIdx.x;
    if (pos >= TOTAL) return;
    int d = dstP[pos];
    u32 i = iOf[pos];
    float e0 = eP[(size_t)pos * 3 + 0];
    float e1 = eP[(size_t)pos * 3 + 1];
    float e2 = eP[(size_t)pos * 3 + 2];
    attn[(size_t)i * 3 + 0] = e0 * rdenom[d * 3 + 0];
    attn[(size_t)i * 3 + 1] = e1 * rdenom[d * 3 + 1];
    attn[(size_t)i * 3 + 2] = e2 * rdenom[d * 3 + 2];
}

// ---------------- head MLP ----------------
__global__ void k_head(const float* __restrict__ psum, const u32* __restrict__ pmax,
                       const int* __restrict__ pcnt, const float* __restrict__ fc1w,
                       const float* __restrict__ fc1b, const float* __restrict__ fc2w,
                       const float* __restrict__ fc2b, float* __restrict__ logits) {
    __shared__ float z[2 * HC];
    int g = blockIdx.x;
    int t = threadIdx.x;   // 0..63
    float cnt = fmaxf((float)pcnt[g], 1.f);
    for (int k = t; k < 2 * HC; k += 64)
        z[k] = (k < HC) ? psum[g * HC + k] / cnt : funmap(pmax[g * HC + (k - HC)]);
    __syncthreads();
    float acc = fc1b[t];
    for (int k = 0; k < 2 * HC; k++) acc += z[k] * fc1w[k * 64 + t];
    acc = fmaxf(acc, 0.f);
    float v = acc * fc2w[t];
#pragma unroll
    for (int off = 32; off; off >>= 1) v += __shfl_xor(v, off, 64);
    if (t == 0) logits[g] = v + fc2b[0];
}

// ---------------- launcher ----------------
extern "C" void kernel_launch(void* const* d_in, const int* in_sizes, int n_in,
                              void* d_out, int out_size, void* d_ws, size_t ws_size,
                              hipStream_t stream) {
    const float* x     = (const float*)d_in[0];
    const float* eattr = (const float*)d_in[1];
    const float* W1    = (const float*)d_in[2];
    const float* as1   = (const float*)d_in[3];
    const float* ad1   = (const float*)d_in[4];
    const float* We1   = (const float*)d_in[5];
    const float* ae1   = (const float*)d_in[6];
    const float* b1    = (const float*)d_in[7];
    const float* W2    = (const float*)d_in[8];
    const float* as2   = (const float*)d_in[9];
    const float* ad2   = (const float*)d_in[10];
    const float* We2   = (const float*)d_in[11];
    const float* ae2   = (const float*)d_in[12];
    const float* b2    = (const float*)d_in[13];
    const float* fc1w  = (const float*)d_in[14];
    const float* fc1b  = (const float*)d_in[15];
    const float* fc2w  = (const float*)d_in[16];
    const float* fc2b  = (const float*)d_in[17];
    const int* ei      = (const int*)d_in[18];
    const int* batch   = (const int*)d_in[19];

    float* logits = (float*)d_out;
    float* attn1  = logits + GG;
    float* attn2  = attn1 + (size_t)TOTAL * 3;

    // workspace layout
    float* bufA    = (float*)d_ws;                   // NN*192  (xh f32, both layers)
    float* eP      = bufA + (size_t)NN * HC;         // TOTAL*3 (unnormalized e, packed)
    int*   srcP    = (int*)(eP + (size_t)TOTAL * 3);
    int*   dstP    = srcP + TOTAL;
    float* eaP     = (float*)(dstP + TOTAL);
    u32*   iOf     = (u32*)(eaP + TOTAL);
    int*   deg     = (int*)(iOf + TOTAL);
    float* attrsum = (float*)(deg + NN);
    float* asrc    = attrsum + NN;                   // N*3
    float* adst    = asrc + NN * 3;                  // N*3
    float* rdenom  = adst + NN * 3;                  // N*3
    u32*   startv  = (u32*)(rdenom + NN * 3);        // N
    u32*   cursor  = startv + NN;                    // N
    u32*   blocksum= cursor + NN;                    // 64
    float* wedot   = (float*)(blocksum + 64);        // 8
    float* psum    = wedot + 8;                      // G*192
    u32*   pmax    = (u32*)(psum + GG * HC);         // G*192
    int*   pcnt    = (int*)(pmax + GG * HC);         // G
    __hip_bfloat16* xb  = (__hip_bfloat16*)(pcnt + 64);        // NPAD*KP1
    __hip_bfloat16* hb  = xb + (size_t)NPAD * KP1;             // NPAD*192
    __hip_bfloat16* Wt1 = hb + (size_t)NPAD * HC;              // 192*KP1
    __hip_bfloat16* Wt2 = Wt1 + (size_t)HC * KP1;              // 192*192

    // zero init
    hipMemsetAsync(deg, 0, NN * sizeof(int), stream);
    hipMemsetAsync(attrsum, 0, NN * sizeof(float), stream);
    hipMemsetAsync(psum, 0, GG * HC * sizeof(float), stream);
    hipMemsetAsync(pcnt, 0, GG * sizeof(int), stream);
    hipMemsetAsync(hb + (size_t)NN * HC, 0, (size_t)(NPAD - NN) * HC * sizeof(__hip_bfloat16), stream);

    // graph structure (shared by both layers) + weight prep
    k_deg<<<(EE + 255) / 256, 256, 0, stream>>>(ei, eattr, deg, attrsum);
    k_scan1<<<49, 1024, 0, stream>>>(deg, startv, blocksum);
    k_scan2<<<1, 64, 0, stream>>>(blocksum, 49);
    k_scan3<<<(NN + 255) / 256, 256, 0, stream>>>(startv, blocksum, cursor, batch, pcnt);
    k_fill<<<(TOTAL + 255) / 256, 256, 0, stream>>>(ei, eattr, attrsum, deg, cursor,
                                                    srcP, dstP, eaP, iOf);
    k_prep<<<(HC * HC + 255) / 256, 256, 0, stream>>>(W1, W2, We1, ae1, We2, ae2,
                                                      Wt1, Wt2, pmax, wedot);
    k_xconv<<<(NPAD * KP1 + 255) / 256, 256, 0, stream>>>(x, xb);

    const int GB = NPAD / 64;   // 782 MFMA blocks

    // ---- layer 1 ----
    k_mfma_gemm<KP1><<<GB, 256, 0, stream>>>(xb, Wt1, as1, ad1, bufA, asrc, adst);
    k_gatherSM<0><<<NN, 192, 0, stream>>>(startv, deg, srcP, eaP, asrc, adst, wedot, 0,
                                          eP, bufA, b1, rdenom, hb, batch, psum, pmax);
    k_attnout<<<(TOTAL + 255) / 256, 256, 0, stream>>>(iOf, dstP, eP, rdenom, attn1);

    // ---- layer 2 ----
    k_mfma_gemm<HC><<<GB, 256, 0, stream>>>(hb, Wt2, as2, ad2, bufA, asrc, adst);
    k_gatherSM<1><<<NN, 192, 0, stream>>>(startv, deg, srcP, eaP, asrc, adst, wedot, 3,
                                          eP, bufA, b2, rdenom, hb, batch, psum, pmax);
    k_attnout<<<(TOTAL + 255) / 256, 256, 0, stream>>>(iOf, dstP, eP, rdenom, attn2);

    // ---- head ----
    k_head<<<GG, 64, 0, stream>>>(psum, pmax, pcnt, fc1w, fc1b, fc2w, fc2b, logits);
}

// Round 5
// 844.902 us; speedup vs baseline: 1.1207x; 1.1207x over previous
//
#include <hip/hip_runtime.h>
#include <hip/hip_bf16.h>

typedef unsigned int u32;
typedef __attribute__((ext_vector_type(8))) short short8;
typedef __attribute__((ext_vector_type(4))) float f32x4;

#define NN 50000
#define NPAD 50048       // padded to 64-row multiple for MFMA blocks
#define EE 800000
#define GG 64
#define HH 3
#define CC 64
#define IN_DIM 75
#define KP1 96           // padded K for layer-1 GEMM
#define HC 192           // H*C
#define TOTAL (EE + NN)  // edge entries incl self loops

// ---------------- helpers ----------------
__device__ __forceinline__ u32 fmap(float f) {
    u32 u = __float_as_uint(f);
    return (u & 0x80000000u) ? ~u : (u | 0x80000000u);
}
__device__ __forceinline__ float funmap(u32 m) {
    u32 u = (m & 0x80000000u) ? (m ^ 0x80000000u) : ~m;
    return __uint_as_float(u);
}

// ---------------- degree + edge-attr sum ----------------
__global__ void k_deg(const int* __restrict__ ei, const float* __restrict__ eattr,
                      int* __restrict__ deg, float* __restrict__ attrsum) {
    int e = blockIdx.x * 256 + threadIdx.x;
    if (e >= EE) return;
    int d = ei[EE + e];
    atomicAdd(&deg[d], 1);
    atomicAdd(&attrsum[d], eattr[e]);
}

// ---------------- prefix scan (deg+1) : 2-level ----------------
__global__ void k_scan1(const int* __restrict__ deg, u32* __restrict__ startv,
                        u32* __restrict__ blocksum) {
    __shared__ u32 sh[1024];
    int t = threadIdx.x;
    int n = blockIdx.x * 1024 + t;
    u32 v = (n < NN) ? (u32)(deg[n] + 1) : 0u;
    u32 val = v;
    sh[t] = val;
    __syncthreads();
    for (int off = 1; off < 1024; off <<= 1) {
        u32 y = (t >= off) ? sh[t - off] : 0u;
        __syncthreads();
        val += y;
        sh[t] = val;
        __syncthreads();
    }
    if (n < NN) startv[n] = val - v;   // block-exclusive
    if (t == 0) blocksum[blockIdx.x] = sh[1023];
}

__global__ void k_scan2(u32* __restrict__ blocksum, int nb) {
    if (threadIdx.x == 0) {
        u32 acc = 0;
        for (int b = 0; b < nb; b++) { u32 t = blocksum[b]; blocksum[b] = acc; acc += t; }
    }
}

// also accumulates per-graph node counts (pcnt) for pooling mean
__global__ void k_scan3(u32* __restrict__ startv, const u32* __restrict__ blocksum,
                        u32* __restrict__ cursor, const int* __restrict__ batch,
                        int* __restrict__ pcnt) {
    int n = blockIdx.x * 256 + threadIdx.x;
    if (n >= NN) return;
    u32 s = startv[n] + blocksum[n >> 10];
    startv[n] = s;
    cursor[n] = s;
    atomicAdd(&pcnt[batch[n]], 1);
}

// fill CSR-ordered streams: srcP/eaP/dstP packed by destination segment; iOf maps pos->entry
__global__ void k_fill(const int* __restrict__ ei, const float* __restrict__ eattr,
                       const float* __restrict__ attrsum, const int* __restrict__ deg,
                       u32* __restrict__ cursor, int* __restrict__ srcP,
                       int* __restrict__ dstP, float* __restrict__ eaP,
                       u32* __restrict__ iOf) {
    int i = blockIdx.x * 256 + threadIdx.x;
    if (i >= TOTAL) return;
    int s, d;
    float ea;
    if (i < EE) {
        s = ei[i]; d = ei[EE + i]; ea = eattr[i];
    } else {
        s = d = i - EE;
        ea = attrsum[s] / fmaxf((float)deg[s], 1.f);
    }
    u32 pos = atomicAdd(&cursor[d], 1u);
    srcP[pos] = s;
    dstP[pos] = d;
    eaP[pos] = ea;
    iOf[pos] = (u32)i;
}

// ---------------- prep: Wt conversions + pmax init + wedot ----------------
__global__ void k_prep(const float* __restrict__ W1, const float* __restrict__ W2,
                       const float* __restrict__ We1, const float* __restrict__ ae1,
                       const float* __restrict__ We2, const float* __restrict__ ae2,
                       __hip_bfloat16* __restrict__ Wt1, __hip_bfloat16* __restrict__ Wt2,
                       u32* __restrict__ pmax, float* __restrict__ wedot) {
    int i = blockIdx.x * 256 + threadIdx.x;
    if (i < HC * KP1) {
        int j = i / KP1, k = i - j * KP1;
        Wt1[i] = __float2bfloat16(k < IN_DIM ? W1[k * HC + j] : 0.f);
    }
    if (i < HC * HC) {
        int j = i / HC, k = i - j * HC;
        Wt2[i] = __float2bfloat16(W2[k * HC + j]);
    }
    if (i < GG * HC) pmax[i] = 0x007FFFFFu;   // fmap(-inf)
    if (blockIdx.x == 0) {
        int w = threadIdx.x >> 6, c = threadIdx.x & 63;
        for (int dd = w; dd < 6; dd += 4) {
            int layer = dd / 3, h = dd - 3 * layer;
            const float* We = layer ? We2 : We1;
            const float* ae = layer ? ae2 : ae1;
            float v = We[h * 64 + c] * ae[h * 64 + c];
#pragma unroll
            for (int off = 32; off; off >>= 1) v += __shfl_xor(v, off, 64);
            if (c == 0) wedot[dd] = v;
        }
    }
}

// xb[NPAD][KP1] bf16, zero-padded rows and k>=IN_DIM
__global__ void k_xconv(const float* __restrict__ x, __hip_bfloat16* __restrict__ xb) {
    int i = blockIdx.x * 256 + threadIdx.x;
    if (i >= NPAD * KP1) return;
    int n = i / KP1, k = i - n * KP1;
    float v = (n < NN && k < IN_DIM) ? x[n * IN_DIM + k] : 0.f;
    xb[i] = __float2bfloat16(v);
}

// ---------------- MFMA GEMM + fused attdot epilogue, bf16 output ----------------
// outb[NPAD,192](bf16) = A[NPAD,KPAD] @ Wt^T; asrc/adst from f32 acc (full precision).
// A row-major bf16 [NPAD][KPAD]; Wt row-major bf16 [192][KPAD] (Wt[j][k]=W[k][j]).
// Block: 256 thr = 4 waves; 64 rows x 192 cols per block; 12 col-frags per wave.
template <int KPAD>
__global__ __launch_bounds__(256) void k_mfma_gemm(const __hip_bfloat16* __restrict__ A,
                                                   const __hip_bfloat16* __restrict__ Wt,
                                                   const float* __restrict__ asrcw,
                                                   const float* __restrict__ adstw,
                                                   __hip_bfloat16* __restrict__ outb,
                                                   float* __restrict__ asrc,
                                                   float* __restrict__ adst) {
    int wid = threadIdx.x >> 6;
    int lane = threadIdx.x & 63;
    int r0 = blockIdx.x * 64 + wid * 16;
    int lr = lane & 15;     // A: row-in-16, B: col-in-16
    int g = lane >> 4;      // k-subgroup (8 elems each)
    const short* Ab = (const short*)A;
    const short* Wb = (const short*)Wt;
    f32x4 acc[12];
#pragma unroll
    for (int f = 0; f < 12; f++) acc[f] = (f32x4){0.f, 0.f, 0.f, 0.f};
#pragma unroll
    for (int k0 = 0; k0 < KPAD; k0 += 32) {
        short8 a = *(const short8*)(Ab + (size_t)(r0 + lr) * KPAD + k0 + 8 * g);
#pragma unroll
        for (int f = 0; f < 12; f++) {
            short8 b = *(const short8*)(Wb + (size_t)(f * 16 + lr) * KPAD + k0 + 8 * g);
            acc[f] = __builtin_amdgcn_mfma_f32_16x16x32_bf16(a, b, acc[f], 0, 0, 0);
        }
    }
    int rbase = r0 + 4 * g;   // D: col = lane&15, row = 4*(lane>>4)+reg
#pragma unroll
    for (int f = 0; f < 12; f++) {
        int col = f * 16 + lr;
#pragma unroll
        for (int r = 0; r < 4; r++) {
            int row = rbase + r;
            if (row < NN) outb[(size_t)row * HC + col] = __float2bfloat16(acc[f][r]);
        }
    }
    // fused attdot: per row, per head, weighted col-sum reduced across 16-lane group
    float asw[12], adw[12];
#pragma unroll
    for (int f = 0; f < 12; f++) {
        asw[f] = asrcw[f * 16 + lr];
        adw[f] = adstw[f * 16 + lr];
    }
#pragma unroll
    for (int h = 0; h < 3; h++) {
#pragma unroll
        for (int r = 0; r < 4; r++) {
            float p = acc[4 * h][r] * asw[4 * h] + acc[4 * h + 1][r] * asw[4 * h + 1] +
                      acc[4 * h + 2][r] * asw[4 * h + 2] + acc[4 * h + 3][r] * asw[4 * h + 3];
            float q = acc[4 * h][r] * adw[4 * h] + acc[4 * h + 1][r] * adw[4 * h + 1] +
                      acc[4 * h + 2][r] * adw[4 * h + 2] + acc[4 * h + 3][r] * adw[4 * h + 3];
#pragma unroll
            for (int off = 1; off < 16; off <<= 1) {
                p += __shfl_xor(p, off, 64);
                q += __shfl_xor(q, off, 64);
            }
            int row = rbase + r;
            if (lr == 0 && row < NN) {
                asrc[row * 3 + h] = p;
                adst[row * 3 + h] = q;
            }
        }
    }
}

// ---------------- e = exp(leakyrelu(alpha)) in PACKED order, streaming (high TLP) ------
__global__ void k_alphaP(const int* __restrict__ srcP, const int* __restrict__ dstP,
                         const float* __restrict__ eaP, const float* __restrict__ asrc,
                         const float* __restrict__ adst, const float* __restrict__ wedot,
                         int woff, float* __restrict__ eP) {
    int p = blockIdx.x * 256 + threadIdx.x;
    if (p >= TOTAL) return;
    int s = srcP[p], d = dstP[p];
    float ea = eaP[p];
#pragma unroll
    for (int h = 0; h < 3; h++) {
        float a = asrc[s * 3 + h] + adst[d * 3 + h] + ea * wedot[woff + h];
        a = (a > 0.f) ? a : 0.2f * a;
        eP[(size_t)p * 3 + h] = __expf(a);
    }
}

// ---------------- single-pass gather: acc += e * xhb[src], sum e (+pool on layer 2) ----
// Reads e sequentially (precomputed, packed), bf16 xh rows randomly.
template <int LAYER2>
__global__ void k_gatherSM(const u32* __restrict__ startv, const int* __restrict__ deg,
                           const int* __restrict__ srcP, const float* __restrict__ eP,
                           const __hip_bfloat16* __restrict__ xhb,
                           const float* __restrict__ bias, float* __restrict__ rdenom,
                           __hip_bfloat16* __restrict__ hb, const int* __restrict__ batch,
                           float* __restrict__ psum, u32* __restrict__ pmax) {
    int n = blockIdx.x;
    int j = threadIdx.x;      // 0..191
    int h = j >> 6, c = j & 63;
    u32 st = startv[n];
    int L = deg[n] + 1;
    const int* sp = srcP + st;
    const float* ep = eP + (size_t)st * 3 + h;

    float acc = 0.f, ssum = 0.f;
    int p = 0;
    for (; p + 4 <= L; p += 4) {
        int s0 = sp[p], s1 = sp[p + 1], s2 = sp[p + 2], s3 = sp[p + 3];
        float e0 = ep[3 * p], e1 = ep[3 * p + 3], e2 = ep[3 * p + 6], e3 = ep[3 * p + 9];
        float x0 = __bfloat162float(xhb[(size_t)s0 * HC + j]);
        float x1 = __bfloat162float(xhb[(size_t)s1 * HC + j]);
        float x2 = __bfloat162float(xhb[(size_t)s2 * HC + j]);
        float x3 = __bfloat162float(xhb[(size_t)s3 * HC + j]);
        acc += e0 * x0;
        acc += e1 * x1;
        acc += e2 * x2;
        acc += e3 * x3;
        ssum += (e0 + e1) + (e2 + e3);
    }
    for (; p < L; p++) {
        int s0 = sp[p];
        float e0 = ep[3 * p];
        float x0 = __bfloat162float(xhb[(size_t)s0 * HC + j]);
        acc += e0 * x0;
        ssum += e0;
    }
    float r = 1.f / (ssum + 1e-16f);
    if (c == 0) rdenom[n * 3 + h] = r;
    float o = acc * r + bias[j];
    o = (o > 0.f) ? o : expm1f(o);
    if (LAYER2) {
        int gi = batch[n];
        atomicAdd(&psum[gi * HC + j], o);
        atomicMax(&pmax[gi * HC + j], fmap(o));
    } else {
        hb[(size_t)n * HC + j] = __float2bfloat16(o);
    }
}

// ---------------- normalized attn, scatter-write in original entry order ----------------
__global__ void k_attnout(const u32* __restrict__ iOf, const int* __restrict__ dstP,
                          const float* __restrict__ eP, const float* __restrict__ rdenom,
                          float* __restrict__ attn) {
    int pos = blockIdx.x * 256 + threadIdx.x;
    if (pos >= TOTAL) return;
    int d = dstP[pos];
    u32 i = iOf[pos];
    float e0 = eP[(size_t)pos * 3 + 0];
    float e1 = eP[(size_t)pos * 3 + 1];
    float e2 = eP[(size_t)pos * 3 + 2];
    attn[(size_t)i * 3 + 0] = e0 * rdenom[d * 3 + 0];
    attn[(size_t)i * 3 + 1] = e1 * rdenom[d * 3 + 1];
    attn[(size_t)i * 3 + 2] = e2 * rdenom[d * 3 + 2];
}

// ---------------- head MLP ----------------
__global__ void k_head(const float* __restrict__ psum, const u32* __restrict__ pmax,
                       const int* __restrict__ pcnt, const float* __restrict__ fc1w,
                       const float* __restrict__ fc1b, const float* __restrict__ fc2w,
                       const float* __restrict__ fc2b, float* __restrict__ logits) {
    __shared__ float z[2 * HC];
    int g = blockIdx.x;
    int t = threadIdx.x;   // 0..63
    float cnt = fmaxf((float)pcnt[g], 1.f);
    for (int k = t; k < 2 * HC; k += 64)
        z[k] = (k < HC) ? psum[g * HC + k] / cnt : funmap(pmax[g * HC + (k - HC)]);
    __syncthreads();
    float acc = fc1b[t];
    for (int k = 0; k < 2 * HC; k++) acc += z[k] * fc1w[k * 64 + t];
    acc = fmaxf(acc, 0.f);
    float v = acc * fc2w[t];
#pragma unroll
    for (int off = 32; off; off >>= 1) v += __shfl_xor(v, off, 64);
    if (t == 0) logits[g] = v + fc2b[0];
}

// ---------------- launcher ----------------
extern "C" void kernel_launch(void* const* d_in, const int* in_sizes, int n_in,
                              void* d_out, int out_size, void* d_ws, size_t ws_size,
                              hipStream_t stream) {
    const float* x     = (const float*)d_in[0];
    const float* eattr = (const float*)d_in[1];
    const float* W1    = (const float*)d_in[2];
    const float* as1   = (const float*)d_in[3];
    const float* ad1   = (const float*)d_in[4];
    const float* We1   = (const float*)d_in[5];
    const float* ae1   = (const float*)d_in[6];
    const float* b1    = (const float*)d_in[7];
    const float* W2    = (const float*)d_in[8];
    const float* as2   = (const float*)d_in[9];
    const float* ad2   = (const float*)d_in[10];
    const float* We2   = (const float*)d_in[11];
    const float* ae2   = (const float*)d_in[12];
    const float* b2    = (const float*)d_in[13];
    const float* fc1w  = (const float*)d_in[14];
    const float* fc1b  = (const float*)d_in[15];
    const float* fc2w  = (const float*)d_in[16];
    const float* fc2b  = (const float*)d_in[17];
    const int* ei      = (const int*)d_in[18];
    const int* batch   = (const int*)d_in[19];

    float* logits = (float*)d_out;
    float* attn1  = logits + GG;
    float* attn2  = attn1 + (size_t)TOTAL * 3;

    // workspace layout
    float* eP      = (float*)d_ws;                   // TOTAL*3 (unnormalized e, packed)
    int*   srcP    = (int*)(eP + (size_t)TOTAL * 3);
    int*   dstP    = srcP + TOTAL;
    float* eaP     = (float*)(dstP + TOTAL);
    u32*   iOf     = (u32*)(eaP + TOTAL);
    int*   deg     = (int*)(iOf + TOTAL);
    float* attrsum = (float*)(deg + NN);
    float* asrc    = attrsum + NN;                   // N*3
    float* adst    = asrc + NN * 3;                  // N*3
    float* rdenom  = adst + NN * 3;                  // N*3
    u32*   startv  = (u32*)(rdenom + NN * 3);        // N
    u32*   cursor  = startv + NN;                    // N
    u32*   blocksum= cursor + NN;                    // 64
    float* wedot   = (float*)(blocksum + 64);        // 8
    float* psum    = wedot + 8;                      // G*192
    u32*   pmax    = (u32*)(psum + GG * HC);         // G*192
    int*   pcnt    = (int*)(pmax + GG * HC);         // G
    __hip_bfloat16* xb  = (__hip_bfloat16*)(pcnt + 64);        // NPAD*KP1  (layer-1 GEMM in)
    __hip_bfloat16* xhb = xb + (size_t)NPAD * KP1;             // NPAD*192  (GEMM out, both layers)
    __hip_bfloat16* hb  = xhb + (size_t)NPAD * HC;             // NPAD*192  (layer-1 h, GEMM2 in)
    __hip_bfloat16* Wt1 = hb + (size_t)NPAD * HC;              // 192*KP1
    __hip_bfloat16* Wt2 = Wt1 + (size_t)HC * KP1;              // 192*192

    // zero init
    hipMemsetAsync(deg, 0, NN * sizeof(int), stream);
    hipMemsetAsync(attrsum, 0, NN * sizeof(float), stream);
    hipMemsetAsync(psum, 0, GG * HC * sizeof(float), stream);
    hipMemsetAsync(pcnt, 0, GG * sizeof(int), stream);
    hipMemsetAsync(hb + (size_t)NN * HC, 0, (size_t)(NPAD - NN) * HC * sizeof(__hip_bfloat16), stream);

    // graph structure (shared by both layers) + weight prep
    k_deg<<<(EE + 255) / 256, 256, 0, stream>>>(ei, eattr, deg, attrsum);
    k_scan1<<<49, 1024, 0, stream>>>(deg, startv, blocksum);
    k_scan2<<<1, 64, 0, stream>>>(blocksum, 49);
    k_scan3<<<(NN + 255) / 256, 256, 0, stream>>>(startv, blocksum, cursor, batch, pcnt);
    k_fill<<<(TOTAL + 255) / 256, 256, 0, stream>>>(ei, eattr, attrsum, deg, cursor,
                                                    srcP, dstP, eaP, iOf);
    k_prep<<<(HC * HC + 255) / 256, 256, 0, stream>>>(W1, W2, We1, ae1, We2, ae2,
                                                      Wt1, Wt2, pmax, wedot);
    k_xconv<<<(NPAD * KP1 + 255) / 256, 256, 0, stream>>>(x, xb);

    const int GB = NPAD / 64;   // 782 MFMA blocks

    // ---- layer 1 ----
    k_mfma_gemm<KP1><<<GB, 256, 0, stream>>>(xb, Wt1, as1, ad1, xhb, asrc, adst);
    k_alphaP<<<(TOTAL + 255) / 256, 256, 0, stream>>>(srcP, dstP, eaP, asrc, adst,
                                                      wedot, 0, eP);
    k_gatherSM<0><<<NN, 192, 0, stream>>>(startv, deg, srcP, eP, xhb, b1, rdenom,
                                          hb, batch, psum, pmax);
    k_attnout<<<(TOTAL + 255) / 256, 256, 0, stream>>>(iOf, dstP, eP, rdenom, attn1);

    // ---- layer 2 ----
    k_mfma_gemm<HC><<<GB, 256, 0, stream>>>(hb, Wt2, as2, ad2, xhb, asrc, adst);
    k_alphaP<<<(TOTAL + 255) / 256, 256, 0, stream>>>(srcP, dstP, eaP, asrc, adst,
                                                      wedot, 3, eP);
    k_gatherSM<1><<<NN, 192, 0, stream>>>(startv, deg, srcP, eP, xhb, b2, rdenom,
                                          hb, batch, psum, pmax);
    k_attnout<<<(TOTAL + 255) / 256, 256, 0, stream>>>(iOf, dstP, eP, rdenom, attn2);

    // ---- head ----
    k_head<<<GG, 64, 0, stream>>>(psum, pmax, pcnt, fc1w, fc1b, fc2w, fc2b, logits);
}

// Round 7
// 652.771 us; speedup vs baseline: 1.4506x; 1.2943x over previous
//
#include <hip/hip_runtime.h>
#include <hip/hip_bf16.h>

typedef unsigned int u32;
typedef __attribute__((ext_vector_type(8))) short short8;
typedef __attribute__((ext_vector_type(4))) float f32x4;

#define NN 50000
#define NPAD 50048       // padded to 64-row multiple for MFMA blocks
#define EE 800000
#define GG 64
#define HH 3
#define CC 64
#define IN_DIM 75
#define KP1 96           // padded K for layer-1 GEMM
#define HC 192           // H*C
#define TOTAL (EE + NN)  // edge entries incl self loops

// ---------------- helpers ----------------
__device__ __forceinline__ u32 fmap(float f) {
    u32 u = __float_as_uint(f);
    return (u & 0x80000000u) ? ~u : (u | 0x80000000u);
}
__device__ __forceinline__ float funmap(u32 m) {
    u32 u = (m & 0x80000000u) ? (m ^ 0x80000000u) : ~m;
    return __uint_as_float(u);
}

// ---------------- degree + edge-attr sum ----------------
__global__ void k_deg(const int* __restrict__ ei, const float* __restrict__ eattr,
                      int* __restrict__ deg, float* __restrict__ attrsum) {
    int e = blockIdx.x * 256 + threadIdx.x;
    if (e >= EE) return;
    int d = ei[EE + e];
    atomicAdd(&deg[d], 1);
    atomicAdd(&attrsum[d], eattr[e]);
}

// ---------------- prefix scan (deg+1) : 2-level ----------------
__global__ void k_scan1(const int* __restrict__ deg, u32* __restrict__ startv,
                        u32* __restrict__ blocksum) {
    __shared__ u32 sh[1024];
    int t = threadIdx.x;
    int n = blockIdx.x * 1024 + t;
    u32 v = (n < NN) ? (u32)(deg[n] + 1) : 0u;
    u32 val = v;
    sh[t] = val;
    __syncthreads();
    for (int off = 1; off < 1024; off <<= 1) {
        u32 y = (t >= off) ? sh[t - off] : 0u;
        __syncthreads();
        val += y;
        sh[t] = val;
        __syncthreads();
    }
    if (n < NN) startv[n] = val - v;   // block-exclusive
    if (t == 0) blocksum[blockIdx.x] = sh[1023];
}

__global__ void k_scan2(u32* __restrict__ blocksum, int nb) {
    if (threadIdx.x == 0) {
        u32 acc = 0;
        for (int b = 0; b < nb; b++) { u32 t = blocksum[b]; blocksum[b] = acc; acc += t; }
    }
}

__global__ void k_scan3(u32* __restrict__ startv, const u32* __restrict__ blocksum,
                        u32* __restrict__ cursor) {
    int n = blockIdx.x * 256 + threadIdx.x;
    if (n >= NN) return;
    u32 s = startv[n] + blocksum[n >> 10];
    startv[n] = s;
    cursor[n] = s;
}

// per-graph node counts via binary search on SORTED batch (no atomics).
// pcnt[g] = lower_bound(batch, g+1) - lower_bound(batch, g)
__global__ void k_gcnt(const int* __restrict__ batch, int* __restrict__ pcnt) {
    int g = threadIdx.x;   // 0..63
    if (g >= GG) return;
    int lo0 = 0, hi0 = NN;        // lower_bound(g)
    while (lo0 < hi0) { int mid = (lo0 + hi0) >> 1; if (batch[mid] < g) lo0 = mid + 1; else hi0 = mid; }
    int lo1 = lo0, hi1 = NN;      // lower_bound(g+1)
    while (lo1 < hi1) { int mid = (lo1 + hi1) >> 1; if (batch[mid] < g + 1) lo1 = mid + 1; else hi1 = mid; }
    pcnt[g] = lo1 - lo0;
}

// fill CSR-ordered streams: srcP/eaP/dstP packed by destination segment; iOf maps pos->entry
__global__ void k_fill(const int* __restrict__ ei, const float* __restrict__ eattr,
                       const float* __restrict__ attrsum, const int* __restrict__ deg,
                       u32* __restrict__ cursor, int* __restrict__ srcP,
                       int* __restrict__ dstP, float* __restrict__ eaP,
                       u32* __restrict__ iOf) {
    int i = blockIdx.x * 256 + threadIdx.x;
    if (i >= TOTAL) return;
    int s, d;
    float ea;
    if (i < EE) {
        s = ei[i]; d = ei[EE + i]; ea = eattr[i];
    } else {
        s = d = i - EE;
        ea = attrsum[s] / fmaxf((float)deg[s], 1.f);
    }
    u32 pos = atomicAdd(&cursor[d], 1u);
    srcP[pos] = s;
    dstP[pos] = d;
    eaP[pos] = ea;
    iOf[pos] = (u32)i;
}

// ---------------- prep: Wt conversions + pmax init + wedot ----------------
__global__ void k_prep(const float* __restrict__ W1, const float* __restrict__ W2,
                       const float* __restrict__ We1, const float* __restrict__ ae1,
                       const float* __restrict__ We2, const float* __restrict__ ae2,
                       __hip_bfloat16* __restrict__ Wt1, __hip_bfloat16* __restrict__ Wt2,
                       u32* __restrict__ pmax, float* __restrict__ wedot) {
    int i = blockIdx.x * 256 + threadIdx.x;
    if (i < HC * KP1) {
        int j = i / KP1, k = i - j * KP1;
        Wt1[i] = __float2bfloat16(k < IN_DIM ? W1[k * HC + j] : 0.f);
    }
    if (i < HC * HC) {
        int j = i / HC, k = i - j * HC;
        Wt2[i] = __float2bfloat16(W2[k * HC + j]);
    }
    if (i < GG * HC) pmax[i] = 0x007FFFFFu;   // fmap(-inf)
    if (blockIdx.x == 0) {
        int w = threadIdx.x >> 6, c = threadIdx.x & 63;
        for (int dd = w; dd < 6; dd += 4) {
            int layer = dd / 3, h = dd - 3 * layer;
            const float* We = layer ? We2 : We1;
            const float* ae = layer ? ae2 : ae1;
            float v = We[h * 64 + c] * ae[h * 64 + c];
#pragma unroll
            for (int off = 32; off; off >>= 1) v += __shfl_xor(v, off, 64);
            if (c == 0) wedot[dd] = v;
        }
    }
}

// xb[NPAD][KP1] bf16, zero-padded rows and k>=IN_DIM
__global__ void k_xconv(const float* __restrict__ x, __hip_bfloat16* __restrict__ xb) {
    int i = blockIdx.x * 256 + threadIdx.x;
    if (i >= NPAD * KP1) return;
    int n = i / KP1, k = i - n * KP1;
    float v = (n < NN && k < IN_DIM) ? x[n * IN_DIM + k] : 0.f;
    xb[i] = __float2bfloat16(v);
}

// ---------------- MFMA GEMM + fused attdot epilogue, bf16 output ----------------
// outb[NPAD,192](bf16) = A[NPAD,KPAD] @ Wt^T; asrc/adst from f32 acc (full precision).
// A row-major bf16 [NPAD][KPAD]; Wt row-major bf16 [192][KPAD] (Wt[j][k]=W[k][j]).
// Block: 256 thr = 4 waves; 64 rows x 192 cols per block; 12 col-frags per wave.
template <int KPAD>
__global__ __launch_bounds__(256) void k_mfma_gemm(const __hip_bfloat16* __restrict__ A,
                                                   const __hip_bfloat16* __restrict__ Wt,
                                                   const float* __restrict__ asrcw,
                                                   const float* __restrict__ adstw,
                                                   __hip_bfloat16* __restrict__ outb,
                                                   float* __restrict__ asrc,
                                                   float* __restrict__ adst) {
    int wid = threadIdx.x >> 6;
    int lane = threadIdx.x & 63;
    int r0 = blockIdx.x * 64 + wid * 16;
    int lr = lane & 15;     // A: row-in-16, B: col-in-16
    int g = lane >> 4;      // k-subgroup (8 elems each)
    const short* Ab = (const short*)A;
    const short* Wb = (const short*)Wt;
    f32x4 acc[12];
#pragma unroll
    for (int f = 0; f < 12; f++) acc[f] = (f32x4){0.f, 0.f, 0.f, 0.f};
#pragma unroll
    for (int k0 = 0; k0 < KPAD; k0 += 32) {
        short8 a = *(const short8*)(Ab + (size_t)(r0 + lr) * KPAD + k0 + 8 * g);
#pragma unroll
        for (int f = 0; f < 12; f++) {
            short8 b = *(const short8*)(Wb + (size_t)(f * 16 + lr) * KPAD + k0 + 8 * g);
            acc[f] = __builtin_amdgcn_mfma_f32_16x16x32_bf16(a, b, acc[f], 0, 0, 0);
        }
    }
    int rbase = r0 + 4 * g;   // D: col = lane&15, row = 4*(lane>>4)+reg
#pragma unroll
    for (int f = 0; f < 12; f++) {
        int col = f * 16 + lr;
#pragma unroll
        for (int r = 0; r < 4; r++) {
            int row = rbase + r;
            if (row < NN) outb[(size_t)row * HC + col] = __float2bfloat16(acc[f][r]);
        }
    }
    // fused attdot: per row, per head, weighted col-sum reduced across 16-lane group
    float asw[12], adw[12];
#pragma unroll
    for (int f = 0; f < 12; f++) {
        asw[f] = asrcw[f * 16 + lr];
        adw[f] = adstw[f * 16 + lr];
    }
#pragma unroll
    for (int h = 0; h < 3; h++) {
#pragma unroll
        for (int r = 0; r < 4; r++) {
            float p = acc[4 * h][r] * asw[4 * h] + acc[4 * h + 1][r] * asw[4 * h + 1] +
                      acc[4 * h + 2][r] * asw[4 * h + 2] + acc[4 * h + 3][r] * asw[4 * h + 3];
            float q = acc[4 * h][r] * adw[4 * h] + acc[4 * h + 1][r] * adw[4 * h + 1] +
                      acc[4 * h + 2][r] * adw[4 * h + 2] + acc[4 * h + 3][r] * adw[4 * h + 3];
#pragma unroll
            for (int off = 1; off < 16; off <<= 1) {
                p += __shfl_xor(p, off, 64);
                q += __shfl_xor(q, off, 64);
            }
            int row = rbase + r;
            if (lr == 0 && row < NN) {
                asrc[row * 3 + h] = p;
                adst[row * 3 + h] = q;
            }
        }
    }
}

// ---------------- e = exp(leakyrelu(alpha)) in PACKED order, streaming (high TLP) ------
__global__ void k_alphaP(const int* __restrict__ srcP, const int* __restrict__ dstP,
                         const float* __restrict__ eaP, const float* __restrict__ asrc,
                         const float* __restrict__ adst, const float* __restrict__ wedot,
                         int woff, float* __restrict__ eP) {
    int p = blockIdx.x * 256 + threadIdx.x;
    if (p >= TOTAL) return;
    int s = srcP[p], d = dstP[p];
    float ea = eaP[p];
#pragma unroll
    for (int h = 0; h < 3; h++) {
        float a = asrc[s * 3 + h] + adst[d * 3 + h] + ea * wedot[woff + h];
        a = (a > 0.f) ? a : 0.2f * a;
        eP[(size_t)p * 3 + h] = __expf(a);
    }
}

// ---------------- single-pass gather: acc += e * xhb[src], sum e (+pool on layer 2) ----
// Reads e sequentially (precomputed, packed), bf16 xh rows randomly. 8-deep unroll
// keeps 8 independent row fetches in flight (latency-bound random gather).
template <int LAYER2>
__global__ void k_gatherSM(const u32* __restrict__ startv, const int* __restrict__ deg,
                           const int* __restrict__ srcP, const float* __restrict__ eP,
                           const __hip_bfloat16* __restrict__ xhb,
                           const float* __restrict__ bias, float* __restrict__ rdenom,
                           __hip_bfloat16* __restrict__ hb, const int* __restrict__ batch,
                           float* __restrict__ psum, u32* __restrict__ pmax) {
    int n = blockIdx.x;
    int j = threadIdx.x;      // 0..191
    int h = j >> 6, c = j & 63;
    u32 st = startv[n];
    int L = deg[n] + 1;
    const int* sp = srcP + st;
    const float* ep = eP + (size_t)st * 3 + h;

    float acc = 0.f, ssum = 0.f;
    int p = 0;
    for (; p + 8 <= L; p += 8) {
        int s0 = sp[p], s1 = sp[p + 1], s2 = sp[p + 2], s3 = sp[p + 3];
        int s4 = sp[p + 4], s5 = sp[p + 5], s6 = sp[p + 6], s7 = sp[p + 7];
        float e0 = ep[3 * p], e1 = ep[3 * p + 3], e2 = ep[3 * p + 6], e3 = ep[3 * p + 9];
        float e4 = ep[3 * p + 12], e5 = ep[3 * p + 15], e6 = ep[3 * p + 18], e7 = ep[3 * p + 21];
        float x0 = __bfloat162float(xhb[(size_t)s0 * HC + j]);
        float x1 = __bfloat162float(xhb[(size_t)s1 * HC + j]);
        float x2 = __bfloat162float(xhb[(size_t)s2 * HC + j]);
        float x3 = __bfloat162float(xhb[(size_t)s3 * HC + j]);
        float x4 = __bfloat162float(xhb[(size_t)s4 * HC + j]);
        float x5 = __bfloat162float(xhb[(size_t)s5 * HC + j]);
        float x6 = __bfloat162float(xhb[(size_t)s6 * HC + j]);
        float x7 = __bfloat162float(xhb[(size_t)s7 * HC + j]);
        acc += e0 * x0; acc += e1 * x1; acc += e2 * x2; acc += e3 * x3;
        acc += e4 * x4; acc += e5 * x5; acc += e6 * x6; acc += e7 * x7;
        ssum += ((e0 + e1) + (e2 + e3)) + ((e4 + e5) + (e6 + e7));
    }
    for (; p < L; p++) {
        int s0 = sp[p];
        float e0 = ep[3 * p];
        float x0 = __bfloat162float(xhb[(size_t)s0 * HC + j]);
        acc += e0 * x0;
        ssum += e0;
    }
    float r = 1.f / (ssum + 1e-16f);
    if (c == 0) rdenom[n * 3 + h] = r;
    float o = acc * r + bias[j];
    o = (o > 0.f) ? o : expm1f(o);
    if (LAYER2) {
        int gi = batch[n];
        atomicAdd(&psum[gi * HC + j], o);
        atomicMax(&pmax[gi * HC + j], fmap(o));
    } else {
        hb[(size_t)n * HC + j] = __float2bfloat16(o);
    }
}

// ---------------- normalized attn, scatter-write in original entry order ----------------
__global__ void k_attnout(const u32* __restrict__ iOf, const int* __restrict__ dstP,
                          const float* __restrict__ eP, const float* __restrict__ rdenom,
                          float* __restrict__ attn) {
    int pos = blockIdx.x * 256 + threadIdx.x;
    if (pos >= TOTAL) return;
    int d = dstP[pos];
    u32 i = iOf[pos];
    float e0 = eP[(size_t)pos * 3 + 0];
    float e1 = eP[(size_t)pos * 3 + 1];
    float e2 = eP[(size_t)pos * 3 + 2];
    attn[(size_t)i * 3 + 0] = e0 * rdenom[d * 3 + 0];
    attn[(size_t)i * 3 + 1] = e1 * rdenom[d * 3 + 1];
    attn[(size_t)i * 3 + 2] = e2 * rdenom[d * 3 + 2];
}

// ---------------- head MLP ----------------
__global__ void k_head(const float* __restrict__ psum, const u32* __restrict__ pmax,
                       const int* __restrict__ pcnt, const float* __restrict__ fc1w,
                       const float* __restrict__ fc1b, const float* __restrict__ fc2w,
                       const float* __restrict__ fc2b, float* __restrict__ logits) {
    __shared__ float z[2 * HC];
    int g = blockIdx.x;
    int t = threadIdx.x;   // 0..63
    float cnt = fmaxf((float)pcnt[g], 1.f);
    for (int k = t; k < 2 * HC; k += 64)
        z[k] = (k < HC) ? psum[g * HC + k] / cnt : funmap(pmax[g * HC + (k - HC)]);
    __syncthreads();
    float acc = fc1b[t];
    for (int k = 0; k < 2 * HC; k++) acc += z[k] * fc1w[k * 64 + t];
    acc = fmaxf(acc, 0.f);
    float v = acc * fc2w[t];
#pragma unroll
    for (int off = 32; off; off >>= 1) v += __shfl_xor(v, off, 64);
    if (t == 0) logits[g] = v + fc2b[0];
}

// ---------------- launcher ----------------
extern "C" void kernel_launch(void* const* d_in, const int* in_sizes, int n_in,
                              void* d_out, int out_size, void* d_ws, size_t ws_size,
                              hipStream_t stream) {
    const float* x     = (const float*)d_in[0];
    const float* eattr = (const float*)d_in[1];
    const float* W1    = (const float*)d_in[2];
    const float* as1   = (const float*)d_in[3];
    const float* ad1   = (const float*)d_in[4];
    const float* We1   = (const float*)d_in[5];
    const float* ae1   = (const float*)d_in[6];
    const float* b1    = (const float*)d_in[7];
    const float* W2    = (const float*)d_in[8];
    const float* as2   = (const float*)d_in[9];
    const float* ad2   = (const float*)d_in[10];
    const float* We2   = (const float*)d_in[11];
    const float* ae2   = (const float*)d_in[12];
    const float* b2    = (const float*)d_in[13];
    const float* fc1w  = (const float*)d_in[14];
    const float* fc1b  = (const float*)d_in[15];
    const float* fc2w  = (const float*)d_in[16];
    const float* fc2b  = (const float*)d_in[17];
    const int* ei      = (const int*)d_in[18];
    const int* batch   = (const int*)d_in[19];

    float* logits = (float*)d_out;
    float* attn1  = logits + GG;
    float* attn2  = attn1 + (size_t)TOTAL * 3;

    // workspace layout
    float* eP      = (float*)d_ws;                   // TOTAL*3 (unnormalized e, packed)
    int*   srcP    = (int*)(eP + (size_t)TOTAL * 3);
    int*   dstP    = srcP + TOTAL;
    float* eaP     = (float*)(dstP + TOTAL);
    u32*   iOf     = (u32*)(eaP + TOTAL);
    int*   deg     = (int*)(iOf + TOTAL);
    float* attrsum = (float*)(deg + NN);
    float* asrc    = attrsum + NN;                   // N*3
    float* adst    = asrc + NN * 3;                  // N*3
    float* rdenom  = adst + NN * 3;                  // N*3
    u32*   startv  = (u32*)(rdenom + NN * 3);        // N
    u32*   cursor  = startv + NN;                    // N
    u32*   blocksum= cursor + NN;                    // 64
    float* wedot   = (float*)(blocksum + 64);        // 8
    float* psum    = wedot + 8;                      // G*192
    u32*   pmax    = (u32*)(psum + GG * HC);         // G*192
    int*   pcnt    = (int*)(pmax + GG * HC);         // G
    __hip_bfloat16* xb  = (__hip_bfloat16*)(pcnt + 64);        // NPAD*KP1  (layer-1 GEMM in)
    __hip_bfloat16* xhb = xb + (size_t)NPAD * KP1;             // NPAD*192  (GEMM out, both layers)
    __hip_bfloat16* hb  = xhb + (size_t)NPAD * HC;             // NPAD*192  (layer-1 h, GEMM2 in)
    __hip_bfloat16* Wt1 = hb + (size_t)NPAD * HC;              // 192*KP1
    __hip_bfloat16* Wt2 = Wt1 + (size_t)HC * KP1;              // 192*192

    // zero init
    hipMemsetAsync(deg, 0, NN * sizeof(int), stream);
    hipMemsetAsync(attrsum, 0, NN * sizeof(float), stream);
    hipMemsetAsync(psum, 0, GG * HC * sizeof(float), stream);
    hipMemsetAsync(hb + (size_t)NN * HC, 0, (size_t)(NPAD - NN) * HC * sizeof(__hip_bfloat16), stream);

    // graph structure (shared by both layers) + weight prep
    k_deg<<<(EE + 255) / 256, 256, 0, stream>>>(ei, eattr, deg, attrsum);
    k_scan1<<<49, 1024, 0, stream>>>(deg, startv, blocksum);
    k_scan2<<<1, 64, 0, stream>>>(blocksum, 49);
    k_scan3<<<(NN + 255) / 256, 256, 0, stream>>>(startv, blocksum, cursor);
    k_gcnt<<<1, 64, 0, stream>>>(batch, pcnt);
    k_fill<<<(TOTAL + 255) / 256, 256, 0, stream>>>(ei, eattr, attrsum, deg, cursor,
                                                    srcP, dstP, eaP, iOf);
    k_prep<<<(HC * HC + 255) / 256, 256, 0, stream>>>(W1, W2, We1, ae1, We2, ae2,
                                                      Wt1, Wt2, pmax, wedot);
    k_xconv<<<(NPAD * KP1 + 255) / 256, 256, 0, stream>>>(x, xb);

    const int GB = NPAD / 64;   // 782 MFMA blocks

    // ---- layer 1 ----
    k_mfma_gemm<KP1><<<GB, 256, 0, stream>>>(xb, Wt1, as1, ad1, xhb, asrc, adst);
    k_alphaP<<<(TOTAL + 255) / 256, 256, 0, stream>>>(srcP, dstP, eaP, asrc, adst,
                                                      wedot, 0, eP);
    k_gatherSM<0><<<NN, 192, 0, stream>>>(startv, deg, srcP, eP, xhb, b1, rdenom,
                                          hb, batch, psum, pmax);
    k_attnout<<<(TOTAL + 255) / 256, 256, 0, stream>>>(iOf, dstP, eP, rdenom, attn1);

    // ---- layer 2 ----
    k_mfma_gemm<HC><<<GB, 256, 0, stream>>>(hb, Wt2, as2, ad2, xhb, asrc, adst);
    k_alphaP<<<(TOTAL + 255) / 256, 256, 0, stream>>>(srcP, dstP, eaP, asrc, adst,
                                                      wedot, 3, eP);
    k_gatherSM<1><<<NN, 192, 0, stream>>>(startv, deg, srcP, eP, xhb, b2, rdenom,
                                          hb, batch, psum, pmax);
    k_attnout<<<(TOTAL + 255) / 256, 256, 0, stream>>>(iOf, dstP, eP, rdenom, attn2);

    // ---- head ----
    k_head<<<GG, 64, 0, stream>>>(psum, pmax, pcnt, fc1w, fc1b, fc2w, fc2b, logits);
}